// Round 3
// baseline (147.397 us; speedup 1.0000x reference)
//
#include <hip/hip_runtime.h>
#include <hip/hip_bf16.h>

namespace {

constexpr int N = 4096;
constexpr int D = 512;
constexpr int BM = 64;    // tile 64x64, ONE WAVE per tile (R17)
constexpr int BK = 64;    // K-step per fragment column-slice (64 fp8 bytes)
constexpr int KITERS = D / BK;  // 8 per phase
constexpr int NB = N / BM;      // 64 block-rows
constexpr int NBLK = NB * (NB + 1) / 2;  // 2080 upper-tri tiles (= 8 * 260)
constexpr int TILEB = BM * BK;  // 4 KB: one 64-row x 64-byte k-slice
constexpr int PANELB = BM * D;  // 32 KB: one 64-row fp8 panel

// workspace layout (bytes)
constexpr size_t OFF_XB  = 0;                          // fp8 X  [N*D]  fragment-major
constexpr size_t OFF_YB  = (size_t)N * D;              // fp8 Y  [N*D]  fragment-major
constexpr size_t OFF_SQX = OFF_YB + (size_t)N * D;     // fp32 ||x_i||^2 [N]
constexpr size_t OFF_SQY = OFF_SQX + (size_t)N * 4;
constexpr size_t OFF_SX  = OFF_SQY + (size_t)N * 4;    // fp32 row sums KX [N]
constexpr size_t OFF_SY  = OFF_SX + (size_t)N * 4;     // fp32 row sums KY [N]
constexpr size_t OFF_T1  = OFF_SY + (size_t)N * 4;     // fp32 scalar sum(KX*KY)
constexpr size_t WS_NEED = OFF_T1 + 4;

// FRAGMENT-MAJOR ws layout: element (row r, k) of a 64x64B slice lives at
//   nib*1024 + quad*256 + cl*16 + pass*8 + j
// with nib=(r>>4)&3, cl=r&15, quad=(k>>3)&3, pass=k>>5, j=k&7.
// An MFMA operand fragment (16 rows x 64B of K) is a CONTIGUOUS 1KB at
// fragment base + lane*16 -- a perfectly coalesced global_load_dwordx4.
//
// R17: ONE WAVE PER 64x64 TILE, acc[4][4] (64 VGPR). R15/R16 nulls proved
// main was never schedule-bound: all prior shapes moved 32 B per output
// element through L2 (~540 MB, ~16us) vs an 8.7us MFMA floor. 64x64/wave
// halves that to 16 B/out (272 MB, ~8us) and raises MFMA:VMEM from 1:1 to
// 4:1. One-wave blocks: no duplication, no intra-block barriers, perfect
// work-queue balance (2080 blocks), no LDS.
// R17b: final_kernel fused via monotonic completion counter in a __device__
// global (immune to workspace poison; multiple-of-NBLK per launch, so
// (old+1)%NBLK==0 selects exactly one last block per launch/replay).
constexpr float D2_SKIP = 240.f;

typedef __attribute__((ext_vector_type(4))) float floatx4;
typedef __attribute__((ext_vector_type(2))) long longx2;

__device__ unsigned g_done;   // zero-initialized at module load; monotonic

__device__ inline unsigned short bf16bits(float f) {
  return __builtin_bit_cast(unsigned short, __float2bfloat16(f));
}

// fp32 -> fp8 e4m3 (OCP) conversion into the fragment-major layout + exact
// fp32 row squared norms. One wave per row; lane handles 8 consecutive
// elements -> one 8B store. Also zeroes sX/sY/T1.
__global__ void prep_kernel(const float* __restrict__ X, const float* __restrict__ Y,
                            unsigned char* __restrict__ Xf8, unsigned char* __restrict__ Yf8,
                            float* __restrict__ sqX, float* __restrict__ sqY,
                            float* __restrict__ sX, float* __restrict__ sY,
                            float* __restrict__ T1) {
  const int wave = threadIdx.x >> 6, lane = threadIdx.x & 63;
  const int row = blockIdx.x * 4 + wave;
  const int m = blockIdx.y;
  const float* __restrict__ src = m ? Y : X;
  unsigned char* __restrict__ dst = m ? Yf8 : Xf8;
  float* __restrict__ dsq = m ? sqY : sqX;

  if (threadIdx.x < 4) {
    float* z = m ? sY : sX;
    z[blockIdx.x * 4 + threadIdx.x] = 0.f;
  }
  if (blockIdx.x == 0 && m == 0 && threadIdx.x == 0) *T1 = 0.f;

  const float4* s4 = (const float4*)(src + (size_t)row * D);
  float4 v0 = s4[lane * 2];
  float4 v1 = s4[lane * 2 + 1];
  float acc = v0.x * v0.x + v0.y * v0.y + v0.z * v0.z + v0.w * v0.w
            + v1.x * v1.x + v1.y * v1.y + v1.z * v1.z + v1.w * v1.w;

  unsigned int w0 = 0, w1 = 0;
  w0 = __builtin_amdgcn_cvt_pk_fp8_f32(v0.x, v0.y, w0, false);
  w0 = __builtin_amdgcn_cvt_pk_fp8_f32(v0.z, v0.w, w0, true);
  w1 = __builtin_amdgcn_cvt_pk_fp8_f32(v1.x, v1.y, w1, false);
  w1 = __builtin_amdgcn_cvt_pk_fp8_f32(v1.z, v1.w, w1, true);
  const unsigned long long pk =
      (unsigned long long)w0 | ((unsigned long long)w1 << 32);

  // destination: k = lane*8 .. +8 of this row, fragment-major address
  const int p    = row >> 6;          // 64-row panel
  const int nib  = (row >> 4) & 3;
  const int cl   = row & 15;
  const int ks   = lane >> 3;         // 64-byte k-slice
  const int pass = (lane >> 2) & 1;
  const int quad = lane & 3;
  const size_t off = (size_t)p * PANELB + (size_t)ks * TILEB +
                     nib * 1024 + quad * 256 + cl * 16 + pass * 8;
  *(unsigned long long*)(dst + off) = pk;

#pragma unroll
  for (int mm = 32; mm >= 1; mm >>= 1) acc += __shfl_xor(acc, mm, 64);
  if (lane == 0) dsq[row] = acc;
}

// Upper-triangular fused Gram+RBF+reductions+final. One 64-thread wave per
// 64x64 tile; operands read directly from fragment-major global (L2-hot).
__launch_bounds__(64, 2)
__global__ void hsic_main(const unsigned char* __restrict__ Xf8,
                          const unsigned char* __restrict__ Yf8,
                          const float* __restrict__ sqX, const float* __restrict__ sqY,
                          float* __restrict__ sX, float* __restrict__ sY,
                          float* __restrict__ T1, float* __restrict__ out) {
  // XCD-contiguous segment swizzle (bijection on [0,2080): 2080 = 8*260)
  const int b = blockIdx.x;
  int idx = (b & 7) * (NBLK / 8) + (b >> 3);

  // triangular decode: idx -> (bI, bJ) with bJ >= bI (row-major triangle)
  const float nf = (float)NB + 0.5f;
  int bI = (int)(nf - sqrtf(nf * nf - 2.0f * (float)idx));
  if (bI < 0) bI = 0;
  if (bI >= NB) bI = NB - 1;
  while (bI * NB - bI * (bI - 1) / 2 > idx) --bI;
  while ((bI + 1) * NB - (bI + 1) * bI / 2 <= idx) ++bI;
  const int bJ = bI + (idx - (bI * NB - bI * (bI - 1) / 2));
  const bool offdiag = (bI != bJ);

  const int lane = threadIdx.x & 63;
  const int quad = lane >> 4, cl = lane & 15;
  const int lane16 = lane << 4;

  const unsigned char* gAx = Xf8 + (size_t)bI * PANELB + lane16;
  const unsigned char* gBx = Xf8 + (size_t)bJ * PANELB + lane16;
  const unsigned char* gAy = Yf8 + (size_t)bI * PANELB + lane16;
  const unsigned char* gBy = Yf8 + (size_t)bJ * PANELB + lane16;

  floatx4 acc[4][4];
#pragma unroll
  for (int i = 0; i < 4; ++i)
#pragma unroll
    for (int j = 0; j < 4; ++j) acc[i][j] = (floatx4){0.f, 0.f, 0.f, 0.f};

  const int Ib = bI * BM;
  const int Jb = bJ * BM;

  // X-phase results carried into the Y epilogue:
  unsigned int kxp[4][4][2];   // kx packed as bf16 pairs (exact for 0/1)
  unsigned int fmask = 0;      // per-fragment wave-uniform "kx nonzero" bits
  float t1l = 0.f;

  // ---- X phase: 8 k-slices, operands straight from global ----
#pragma unroll
  for (int ks = 0; ks < KITERS; ++ks) {
    longx2 af[4], bf[4];
#pragma unroll
    for (int mi = 0; mi < 4; ++mi)
      af[mi] = *(const longx2*)(gAx + (size_t)ks * TILEB + mi * 1024);
#pragma unroll
    for (int ni = 0; ni < 4; ++ni)
      bf[ni] = *(const longx2*)(gBx + (size_t)ks * TILEB + ni * 1024);
#pragma unroll
    for (int mi = 0; mi < 4; ++mi)
#pragma unroll
      for (int ni = 0; ni < 4; ++ni) {
        acc[mi][ni] = __builtin_amdgcn_mfma_f32_16x16x32_fp8_fp8(af[mi][0], bf[ni][0], acc[mi][ni], 0, 0, 0);
        acc[mi][ni] = __builtin_amdgcn_mfma_f32_16x16x32_fp8_fp8(af[mi][1], bf[ni][1], acc[mi][ni], 0, 0, 0);
      }
  }

  // ---- X epilogue: acc -> kx; sX atomics; pack kx; reset acc ----
  // C/D layout (m89): col = lane&15, row = quad*4 + reg
  {
    float rx[4][4];
    float cx[4];
#pragma unroll
    for (int mi = 0; mi < 4; ++mi)
#pragma unroll
      for (int r = 0; r < 4; ++r) rx[mi][r] = 0.f;
#pragma unroll
    for (int ni = 0; ni < 4; ++ni) cx[ni] = 0.f;

#pragma unroll
    for (int mi = 0; mi < 4; ++mi) {
      const int ig0 = Ib + mi * 16 + quad * 4;
      float sxi[4];
#pragma unroll
      for (int r = 0; r < 4; ++r) sxi[r] = sqX[ig0 + r];
#pragma unroll
      for (int ni = 0; ni < 4; ++ni) {
        const int jg = Jb + ni * 16 + cl;
        const float sxj = sqX[jg];
        float d2x[4];
        bool lflag = false;
#pragma unroll
        for (int r = 0; r < 4; ++r) {
          const int ig = ig0 + r;
          d2x[r] = sxi[r] + sxj - 2.f * acc[mi][ni][r];
          lflag |= (d2x[r] < D2_SKIP) | (ig == jg);
        }
        float kxv[4] = {0.f, 0.f, 0.f, 0.f};
        if (__any(lflag)) {   // wave-uniform; skipped frags are exactly 0
          fmask |= (1u << (mi * 4 + ni));
#pragma unroll
          for (int r = 0; r < 4; ++r) {
            const int ig = ig0 + r;
            kxv[r] = (ig == jg) ? 1.f : __expf(-0.5f * d2x[r]);
            rx[mi][r] += kxv[r];
            cx[ni] += kxv[r];
          }
        }
        kxp[mi][ni][0] = (unsigned)bf16bits(kxv[0]) | ((unsigned)bf16bits(kxv[1]) << 16);
        kxp[mi][ni][1] = (unsigned)bf16bits(kxv[2]) | ((unsigned)bf16bits(kxv[3]) << 16);
        // reset acc for the Y phase
        acc[mi][ni] = (floatx4){0.f, 0.f, 0.f, 0.f};
      }
    }

    if (fmask != 0) {
      // row sums: reduce across the 16 columns (lanes cl=0..15 per quad)
#pragma unroll
      for (int mi = 0; mi < 4; ++mi)
#pragma unroll
        for (int r = 0; r < 4; ++r) {
          float vx = rx[mi][r];
#pragma unroll
          for (int mm = 1; mm < 16; mm <<= 1) vx += __shfl_xor(vx, mm, 16);
          rx[mi][r] = vx;
        }
      if (cl == 0) {
#pragma unroll
        for (int mi = 0; mi < 4; ++mi)
#pragma unroll
          for (int r = 0; r < 4; ++r)
            atomicAdd(&sX[Ib + mi * 16 + quad * 4 + r], rx[mi][r]);
      }
      if (offdiag) {
#pragma unroll
        for (int ni = 0; ni < 4; ++ni) {
          float vx = cx[ni];
          vx += __shfl_xor(vx, 16, 64);
          vx += __shfl_xor(vx, 32, 64);
          if (quad == 0) atomicAdd(&sX[Jb + ni * 16 + cl], vx);
        }
      }
    }
  }

  // ---- Y phase ----
#pragma unroll
  for (int ks = 0; ks < KITERS; ++ks) {
    longx2 af[4], bf[4];
#pragma unroll
    for (int mi = 0; mi < 4; ++mi)
      af[mi] = *(const longx2*)(gAy + (size_t)ks * TILEB + mi * 1024);
#pragma unroll
    for (int ni = 0; ni < 4; ++ni)
      bf[ni] = *(const longx2*)(gBy + (size_t)ks * TILEB + ni * 1024);
#pragma unroll
    for (int mi = 0; mi < 4; ++mi)
#pragma unroll
      for (int ni = 0; ni < 4; ++ni) {
        acc[mi][ni] = __builtin_amdgcn_mfma_f32_16x16x32_fp8_fp8(af[mi][0], bf[ni][0], acc[mi][ni], 0, 0, 0);
        acc[mi][ni] = __builtin_amdgcn_mfma_f32_16x16x32_fp8_fp8(af[mi][1], bf[ni][1], acc[mi][ni], 0, 0, 0);
      }
  }

  // ---- Y epilogue ----
  {
    float ry[4][4];
    float cy[4];
    bool anyy = false;
#pragma unroll
    for (int mi = 0; mi < 4; ++mi)
#pragma unroll
      for (int r = 0; r < 4; ++r) ry[mi][r] = 0.f;
#pragma unroll
    for (int ni = 0; ni < 4; ++ni) cy[ni] = 0.f;

#pragma unroll
    for (int mi = 0; mi < 4; ++mi) {
      const int ig0 = Ib + mi * 16 + quad * 4;
      float syi[4];
#pragma unroll
      for (int r = 0; r < 4; ++r) syi[r] = sqY[ig0 + r];
#pragma unroll
      for (int ni = 0; ni < 4; ++ni) {
        const int jg = Jb + ni * 16 + cl;
        const float syj = sqY[jg];
        float d2y[4];
        bool lflag = false;
#pragma unroll
        for (int r = 0; r < 4; ++r) {
          const int ig = ig0 + r;
          d2y[r] = syi[r] + syj - 2.f * acc[mi][ni][r];
          lflag |= (d2y[r] < D2_SKIP) | (ig == jg);
        }
        const bool xb = (fmask >> (mi * 4 + ni)) & 1u;  // wave-uniform
        if (__any(lflag) || xb) {
          anyy = true;
          float kyv[4];
#pragma unroll
          for (int r = 0; r < 4; ++r) {
            const int ig = ig0 + r;
            kyv[r] = (ig == jg) ? 1.f : __expf(-0.5f * d2y[r]);
            ry[mi][r] += kyv[r];
            cy[ni] += kyv[r];
          }
          if (xb) {
            const float kx0 = __builtin_bit_cast(float, (kxp[mi][ni][0] & 0xFFFFu) << 16);
            const float kx1 = __builtin_bit_cast(float, kxp[mi][ni][0] & 0xFFFF0000u);
            const float kx2 = __builtin_bit_cast(float, (kxp[mi][ni][1] & 0xFFFFu) << 16);
            const float kx3 = __builtin_bit_cast(float, kxp[mi][ni][1] & 0xFFFF0000u);
            t1l += kx0 * kyv[0] + kx1 * kyv[1] + kx2 * kyv[2] + kx3 * kyv[3];
          }
        }
      }
    }

    if (anyy) {
#pragma unroll
      for (int mi = 0; mi < 4; ++mi)
#pragma unroll
        for (int r = 0; r < 4; ++r) {
          float vy = ry[mi][r];
#pragma unroll
          for (int mm = 1; mm < 16; mm <<= 1) vy += __shfl_xor(vy, mm, 16);
          ry[mi][r] = vy;
        }
      if (cl == 0) {
#pragma unroll
        for (int mi = 0; mi < 4; ++mi)
#pragma unroll
          for (int r = 0; r < 4; ++r)
            atomicAdd(&sY[Ib + mi * 16 + quad * 4 + r], ry[mi][r]);
      }
      if (offdiag) {
#pragma unroll
        for (int ni = 0; ni < 4; ++ni) {
          float vy = cy[ni];
          vy += __shfl_xor(vy, 16, 64);
          vy += __shfl_xor(vy, 32, 64);
          if (quad == 0) atomicAdd(&sY[Jb + ni * 16 + cl], vy);
        }
      }
    }
  }

  // T1 wave reduction (off-diagonal tiles count twice by symmetry)
  if (fmask != 0) {
    t1l *= offdiag ? 2.f : 1.f;
#pragma unroll
    for (int mm = 1; mm < 64; mm <<= 1) t1l += __shfl_xor(t1l, mm, 64);
    if (lane == 0 && t1l != 0.f) atomicAdd(T1, t1l);
  }

  // ---- fused final: completion counter; last block computes HSIC ----
  // All prior device-scope atomics (sX/sY/T1) are ordered before each
  // block's release fetch_add; the last block's acquire read of the counter
  // makes them visible to its relaxed atomic loads. g_done is a __device__
  // global: unaffected by workspace poison, monotonic across launches and
  // rocprof replays (each adds exactly NBLK).
  int am_last = 0;
  if (lane == 0) {
    unsigned old = __hip_atomic_fetch_add(&g_done, 1u, __ATOMIC_ACQ_REL,
                                          __HIP_MEMORY_SCOPE_AGENT);
    am_last = ((old + 1u) % (unsigned)NBLK) == 0u;
  }
  am_last = __shfl(am_last, 0, 64);
  if (am_last) {
    float dp = 0.f, sa = 0.f, sb = 0.f;
    for (int i = lane; i < N; i += 64) {
      float a = __hip_atomic_load(&sX[i], __ATOMIC_RELAXED, __HIP_MEMORY_SCOPE_AGENT);
      float bv = __hip_atomic_load(&sY[i], __ATOMIC_RELAXED, __HIP_MEMORY_SCOPE_AGENT);
      dp += a * bv; sa += a; sb += bv;
    }
#pragma unroll
    for (int mm = 1; mm < 64; mm <<= 1) {
      dp += __shfl_xor(dp, mm, 64);
      sa += __shfl_xor(sa, mm, 64);
      sb += __shfl_xor(sb, mm, 64);
    }
    if (lane == 0) {
      const float t1 = __hip_atomic_load(T1, __ATOMIC_RELAXED, __HIP_MEMORY_SCOPE_AGENT);
      const float n = (float)N;
      const float total = t1 - (2.f / n) * dp + (sa * sb) / (n * n);
      out[0] = total / ((n - 1.f) * (n - 1.f));
    }
  }
}

}  // namespace

extern "C" void kernel_launch(void* const* d_in, const int* in_sizes, int n_in,
                              void* d_out, int out_size, void* d_ws, size_t ws_size,
                              hipStream_t stream) {
  const float* X = (const float*)d_in[0];
  const float* Y = (const float*)d_in[1];
  char* ws = (char*)d_ws;
  if (ws_size < WS_NEED) return;

  unsigned char* Xf8 = (unsigned char*)(ws + OFF_XB);
  unsigned char* Yf8 = (unsigned char*)(ws + OFF_YB);
  float* sqX = (float*)(ws + OFF_SQX);
  float* sqY = (float*)(ws + OFF_SQY);
  float* sX  = (float*)(ws + OFF_SX);
  float* sY  = (float*)(ws + OFF_SY);
  float* T1  = (float*)(ws + OFF_T1);
  float* out = (float*)d_out;

  prep_kernel<<<dim3(N / 4, 2), 256, 0, stream>>>(X, Y, Xf8, Yf8, sqX, sqY, sX, sY, T1);
  hsic_main<<<NBLK, 64, 0, stream>>>(Xf8, Yf8, sqX, sqY, sX, sY, T1, out);
}

// Round 4
// 147.153 us; speedup vs baseline: 1.0017x; 1.0017x over previous
//
#include <hip/hip_runtime.h>
#include <hip/hip_bf16.h>

namespace {

constexpr int N = 4096;
constexpr int D = 512;
constexpr int BM = 64;    // tile 64x64, one WAVE per tile; 4 tiles per block (R18)
constexpr int BK = 64;    // K-step per fragment column-slice (64 fp8 bytes)
constexpr int KITERS = D / BK;  // 8 per phase
constexpr int NB = N / BM;      // 64 block-rows
constexpr int NBLK = NB * (NB + 1) / 2;  // 2080 upper-tri tiles (= 8 * 260)
constexpr int NGRID = NBLK / 4;          // 520 blocks x 4 waves
constexpr int TILEB = BM * BK;  // 4 KB: one 64-row x 64-byte k-slice
constexpr int PANELB = BM * D;  // 32 KB: one 64-row fp8 panel

// workspace layout (bytes)
constexpr size_t OFF_XB  = 0;                          // fp8 X  [N*D]  fragment-major
constexpr size_t OFF_YB  = (size_t)N * D;              // fp8 Y  [N*D]  fragment-major
constexpr size_t OFF_SQX = OFF_YB + (size_t)N * D;     // fp32 ||x_i||^2 [N]
constexpr size_t OFF_SQY = OFF_SQX + (size_t)N * 4;
constexpr size_t OFF_SX  = OFF_SQY + (size_t)N * 4;    // fp32 row sums KX [N]
constexpr size_t OFF_SY  = OFF_SX + (size_t)N * 4;     // fp32 row sums KY [N]
constexpr size_t OFF_T1  = OFF_SY + (size_t)N * 4;     // fp32 scalar sum(KX*KY)
constexpr size_t WS_NEED = OFF_T1 + 4;

// FRAGMENT-MAJOR ws layout: element (row r, k) of a 64x64B slice lives at
//   nib*1024 + quad*256 + cl*16 + pass*8 + j
// with nib=(r>>4)&3, cl=r&15, quad=(k>>3)&3, pass=k>>5, j=k&7.
// An MFMA operand fragment (16 rows x 64B of K) is a CONTIGUOUS 1KB at
// fragment base + lane*16 -- a perfectly coalesced global_load_dwordx4.
//
// R18: R17's 64-thread blocks collapsed occupancy (12.6%, main=92us,
// MfmaUtil 6.9% -- loads latency-serialized at ~190cy each, effectively
// ~1 wave/CU). Fix both causes, keep the 16 B/output efficiency:
//   (a) 256-thread blocks, 4 INDEPENDENT waves, each its own 64x64 tile
//       (consecutive swizzled triangle indices -> shared A panel in L1);
//   (b) explicit 2-set software pipeline: preload fragment set k+1 into
//       alternate registers BEFORE the MFMAs of set k (fully unrolled,
//       static) so the 8 loads stay in flight across ~544cy of MFMA.
// Fused final via monotonic __device__ wave-completion counter (R17b,
// verified bit-exact): immune to workspace poison, exactly NBLK waves per
// launch/replay, (old+1)%NBLK==0 selects the last wave.
constexpr float D2_SKIP = 240.f;

typedef __attribute__((ext_vector_type(4))) float floatx4;
typedef __attribute__((ext_vector_type(2))) long longx2;

__device__ unsigned g_done;   // zero-initialized at module load; monotonic

__device__ inline unsigned short bf16bits(float f) {
  return __builtin_bit_cast(unsigned short, __float2bfloat16(f));
}

// fp32 -> fp8 e4m3 (OCP) conversion into the fragment-major layout + exact
// fp32 row squared norms. One wave per row; lane handles 8 consecutive
// elements -> one 8B store. Also zeroes sX/sY/T1.
__global__ void prep_kernel(const float* __restrict__ X, const float* __restrict__ Y,
                            unsigned char* __restrict__ Xf8, unsigned char* __restrict__ Yf8,
                            float* __restrict__ sqX, float* __restrict__ sqY,
                            float* __restrict__ sX, float* __restrict__ sY,
                            float* __restrict__ T1) {
  const int wave = threadIdx.x >> 6, lane = threadIdx.x & 63;
  const int row = blockIdx.x * 4 + wave;
  const int m = blockIdx.y;
  const float* __restrict__ src = m ? Y : X;
  unsigned char* __restrict__ dst = m ? Yf8 : Xf8;
  float* __restrict__ dsq = m ? sqY : sqX;

  if (threadIdx.x < 4) {
    float* z = m ? sY : sX;
    z[blockIdx.x * 4 + threadIdx.x] = 0.f;
  }
  if (blockIdx.x == 0 && m == 0 && threadIdx.x == 0) *T1 = 0.f;

  const float4* s4 = (const float4*)(src + (size_t)row * D);
  float4 v0 = s4[lane * 2];
  float4 v1 = s4[lane * 2 + 1];
  float acc = v0.x * v0.x + v0.y * v0.y + v0.z * v0.z + v0.w * v0.w
            + v1.x * v1.x + v1.y * v1.y + v1.z * v1.z + v1.w * v1.w;

  unsigned int w0 = 0, w1 = 0;
  w0 = __builtin_amdgcn_cvt_pk_fp8_f32(v0.x, v0.y, w0, false);
  w0 = __builtin_amdgcn_cvt_pk_fp8_f32(v0.z, v0.w, w0, true);
  w1 = __builtin_amdgcn_cvt_pk_fp8_f32(v1.x, v1.y, w1, false);
  w1 = __builtin_amdgcn_cvt_pk_fp8_f32(v1.z, v1.w, w1, true);
  const unsigned long long pk =
      (unsigned long long)w0 | ((unsigned long long)w1 << 32);

  // destination: k = lane*8 .. +8 of this row, fragment-major address
  const int p    = row >> 6;          // 64-row panel
  const int nib  = (row >> 4) & 3;
  const int cl   = row & 15;
  const int ks   = lane >> 3;         // 64-byte k-slice
  const int pass = (lane >> 2) & 1;
  const int quad = lane & 3;
  const size_t off = (size_t)p * PANELB + (size_t)ks * TILEB +
                     nib * 1024 + quad * 256 + cl * 16 + pass * 8;
  *(unsigned long long*)(dst + off) = pk;

#pragma unroll
  for (int mm = 32; mm >= 1; mm >>= 1) acc += __shfl_xor(acc, mm, 64);
  if (lane == 0) dsq[row] = acc;
}

// Upper-triangular fused Gram+RBF+reductions+final. 256 threads = 4
// independent waves, each owning one 64x64 tile; operands read directly
// from fragment-major global (L2/L3-hot) with a 2-set register pipeline.
__launch_bounds__(256, 2)
__global__ void hsic_main(const unsigned char* __restrict__ Xf8,
                          const unsigned char* __restrict__ Yf8,
                          const float* __restrict__ sqX, const float* __restrict__ sqY,
                          float* __restrict__ sX, float* __restrict__ sY,
                          float* __restrict__ T1, float* __restrict__ out) {
  const int tid = threadIdx.x;
  const int lane = tid & 63, wave = tid >> 6;

  // XCD-contiguous segment swizzle at block level; 4 consecutive tile
  // indices per block (one per wave). Bijection on [0,2080):
  // 520 blocks = 8 segments x 65; idx = seg*260 + (b>>3)*4 + wave.
  const int b = blockIdx.x;
  const int idx = (b & 7) * (NBLK / 8) + (b >> 3) * 4 + wave;

  // triangular decode: idx -> (bI, bJ) with bJ >= bI (row-major triangle)
  const float nf = (float)NB + 0.5f;
  int bI = (int)(nf - sqrtf(nf * nf - 2.0f * (float)idx));
  if (bI < 0) bI = 0;
  if (bI >= NB) bI = NB - 1;
  while (bI * NB - bI * (bI - 1) / 2 > idx) --bI;
  while ((bI + 1) * NB - (bI + 1) * bI / 2 <= idx) ++bI;
  const int bJ = bI + (idx - (bI * NB - bI * (bI - 1) / 2));
  const bool offdiag = (bI != bJ);

  const int quad = lane >> 4, cl = lane & 15;
  const int lane16 = lane << 4;

  const unsigned char* gAx = Xf8 + (size_t)bI * PANELB + lane16;
  const unsigned char* gBx = Xf8 + (size_t)bJ * PANELB + lane16;
  const unsigned char* gAy = Yf8 + (size_t)bI * PANELB + lane16;
  const unsigned char* gBy = Yf8 + (size_t)bJ * PANELB + lane16;

  floatx4 acc[4][4];
#pragma unroll
  for (int i = 0; i < 4; ++i)
#pragma unroll
    for (int j = 0; j < 4; ++j) acc[i][j] = (floatx4){0.f, 0.f, 0.f, 0.f};

  const int Ib = bI * BM;
  const int Jb = bJ * BM;

  // X-phase results carried into the Y epilogue:
  unsigned int kxp[4][4][2];   // kx packed as bf16 pairs (exact for 0/1)
  unsigned int fmask = 0;      // per-fragment wave-uniform "kx nonzero" bits
  float t1l = 0.f;

  // two register sets for the software pipeline (all statically indexed)
  longx2 aP[4], bP[4], aQ[4], bQ[4];

  auto loadset = [&](longx2* a, longx2* bb, const unsigned char* gA,
                     const unsigned char* gB, int ks) {
#pragma unroll
    for (int mi = 0; mi < 4; ++mi)
      a[mi] = *(const longx2*)(gA + (size_t)ks * TILEB + mi * 1024);
#pragma unroll
    for (int ni = 0; ni < 4; ++ni)
      bb[ni] = *(const longx2*)(gB + (size_t)ks * TILEB + ni * 1024);
  };
  auto mfmaset = [&](const longx2* a, const longx2* bb) {
#pragma unroll
    for (int mi = 0; mi < 4; ++mi)
#pragma unroll
      for (int ni = 0; ni < 4; ++ni) {
        acc[mi][ni] = __builtin_amdgcn_mfma_f32_16x16x32_fp8_fp8(a[mi][0], bb[ni][0], acc[mi][ni], 0, 0, 0);
        acc[mi][ni] = __builtin_amdgcn_mfma_f32_16x16x32_fp8_fp8(a[mi][1], bb[ni][1], acc[mi][ni], 0, 0, 0);
      }
  };

  // ---- X phase: preload k=0; each iter prefetches k+1 into the idle set
  // BEFORE computing on the current set. Last iter prefetches Y's k=0, so
  // those loads fly across the X epilogue's VALU work.
  loadset(aP, bP, gAx, gBx, 0);
#pragma unroll
  for (int k = 0; k < KITERS; ++k) {
    if ((k & 1) == 0) {
      if (k + 1 < KITERS) loadset(aQ, bQ, gAx, gBx, k + 1);
      else                loadset(aQ, bQ, gAy, gBy, 0);
      mfmaset(aP, bP);
    } else {
      if (k + 1 < KITERS) loadset(aP, bP, gAx, gBx, k + 1);
      else                loadset(aP, bP, gAy, gBy, 0);
      mfmaset(aQ, bQ);
    }
  }
  // Y phase k=0 now sits in aQ/bQ (KITERS even: last X iter filled Q? No --
  // KITERS=8: k=7 is odd -> filled aP/bP with Y k=0, computed on Q.)
  // => Y's k=0 is in P.

  // ---- X epilogue: acc -> kx; sX atomics; pack kx; reset acc ----
  // C/D layout (m89): col = lane&15, row = quad*4 + reg
  {
    float rx[4][4];
    float cx[4];
#pragma unroll
    for (int mi = 0; mi < 4; ++mi)
#pragma unroll
      for (int r = 0; r < 4; ++r) rx[mi][r] = 0.f;
#pragma unroll
    for (int ni = 0; ni < 4; ++ni) cx[ni] = 0.f;

#pragma unroll
    for (int mi = 0; mi < 4; ++mi) {
      const int ig0 = Ib + mi * 16 + quad * 4;
      float sxi[4];
#pragma unroll
      for (int r = 0; r < 4; ++r) sxi[r] = sqX[ig0 + r];
#pragma unroll
      for (int ni = 0; ni < 4; ++ni) {
        const int jg = Jb + ni * 16 + cl;
        const float sxj = sqX[jg];
        float d2x[4];
        bool lflag = false;
#pragma unroll
        for (int r = 0; r < 4; ++r) {
          const int ig = ig0 + r;
          d2x[r] = sxi[r] + sxj - 2.f * acc[mi][ni][r];
          lflag |= (d2x[r] < D2_SKIP) | (ig == jg);
        }
        float kxv[4] = {0.f, 0.f, 0.f, 0.f};
        if (__any(lflag)) {   // wave-uniform; skipped frags are exactly 0
          fmask |= (1u << (mi * 4 + ni));
#pragma unroll
          for (int r = 0; r < 4; ++r) {
            const int ig = ig0 + r;
            kxv[r] = (ig == jg) ? 1.f : __expf(-0.5f * d2x[r]);
            rx[mi][r] += kxv[r];
            cx[ni] += kxv[r];
          }
        }
        kxp[mi][ni][0] = (unsigned)bf16bits(kxv[0]) | ((unsigned)bf16bits(kxv[1]) << 16);
        kxp[mi][ni][1] = (unsigned)bf16bits(kxv[2]) | ((unsigned)bf16bits(kxv[3]) << 16);
        // reset acc for the Y phase
        acc[mi][ni] = (floatx4){0.f, 0.f, 0.f, 0.f};
      }
    }

    if (fmask != 0) {
      // row sums: reduce across the 16 columns (lanes cl=0..15 per quad)
#pragma unroll
      for (int mi = 0; mi < 4; ++mi)
#pragma unroll
        for (int r = 0; r < 4; ++r) {
          float vx = rx[mi][r];
#pragma unroll
          for (int mm = 1; mm < 16; mm <<= 1) vx += __shfl_xor(vx, mm, 16);
          rx[mi][r] = vx;
        }
      if (cl == 0) {
#pragma unroll
        for (int mi = 0; mi < 4; ++mi)
#pragma unroll
          for (int r = 0; r < 4; ++r)
            atomicAdd(&sX[Ib + mi * 16 + quad * 4 + r], rx[mi][r]);
      }
      if (offdiag) {
#pragma unroll
        for (int ni = 0; ni < 4; ++ni) {
          float vx = cx[ni];
          vx += __shfl_xor(vx, 16, 64);
          vx += __shfl_xor(vx, 32, 64);
          if (quad == 0) atomicAdd(&sX[Jb + ni * 16 + cl], vx);
        }
      }
    }
  }

  // ---- Y phase (k=0 already in flight/in P from the X loop's tail) ----
#pragma unroll
  for (int k = 0; k < KITERS; ++k) {
    if ((k & 1) == 0) {
      if (k + 1 < KITERS) loadset(aQ, bQ, gAy, gBy, k + 1);
      mfmaset(aP, bP);
    } else {
      if (k + 1 < KITERS) loadset(aP, bP, gAy, gBy, k + 1);
      mfmaset(aQ, bQ);
    }
  }

  // ---- Y epilogue ----
  {
    float ry[4][4];
    float cy[4];
    bool anyy = false;
#pragma unroll
    for (int mi = 0; mi < 4; ++mi)
#pragma unroll
      for (int r = 0; r < 4; ++r) ry[mi][r] = 0.f;
#pragma unroll
    for (int ni = 0; ni < 4; ++ni) cy[ni] = 0.f;

#pragma unroll
    for (int mi = 0; mi < 4; ++mi) {
      const int ig0 = Ib + mi * 16 + quad * 4;
      float syi[4];
#pragma unroll
      for (int r = 0; r < 4; ++r) syi[r] = sqY[ig0 + r];
#pragma unroll
      for (int ni = 0; ni < 4; ++ni) {
        const int jg = Jb + ni * 16 + cl;
        const float syj = sqY[jg];
        float d2y[4];
        bool lflag = false;
#pragma unroll
        for (int r = 0; r < 4; ++r) {
          const int ig = ig0 + r;
          d2y[r] = syi[r] + syj - 2.f * acc[mi][ni][r];
          lflag |= (d2y[r] < D2_SKIP) | (ig == jg);
        }
        const bool xb = (fmask >> (mi * 4 + ni)) & 1u;  // wave-uniform
        if (__any(lflag) || xb) {
          anyy = true;
          float kyv[4];
#pragma unroll
          for (int r = 0; r < 4; ++r) {
            const int ig = ig0 + r;
            kyv[r] = (ig == jg) ? 1.f : __expf(-0.5f * d2y[r]);
            ry[mi][r] += kyv[r];
            cy[ni] += kyv[r];
          }
          if (xb) {
            const float kx0 = __builtin_bit_cast(float, (kxp[mi][ni][0] & 0xFFFFu) << 16);
            const float kx1 = __builtin_bit_cast(float, kxp[mi][ni][0] & 0xFFFF0000u);
            const float kx2 = __builtin_bit_cast(float, (kxp[mi][ni][1] & 0xFFFFu) << 16);
            const float kx3 = __builtin_bit_cast(float, kxp[mi][ni][1] & 0xFFFF0000u);
            t1l += kx0 * kyv[0] + kx1 * kyv[1] + kx2 * kyv[2] + kx3 * kyv[3];
          }
        }
      }
    }

    if (anyy) {
#pragma unroll
      for (int mi = 0; mi < 4; ++mi)
#pragma unroll
        for (int r = 0; r < 4; ++r) {
          float vy = ry[mi][r];
#pragma unroll
          for (int mm = 1; mm < 16; mm <<= 1) vy += __shfl_xor(vy, mm, 16);
          ry[mi][r] = vy;
        }
      if (cl == 0) {
#pragma unroll
        for (int mi = 0; mi < 4; ++mi)
#pragma unroll
          for (int r = 0; r < 4; ++r)
            atomicAdd(&sY[Ib + mi * 16 + quad * 4 + r], ry[mi][r]);
      }
      if (offdiag) {
#pragma unroll
        for (int ni = 0; ni < 4; ++ni) {
          float vy = cy[ni];
          vy += __shfl_xor(vy, 16, 64);
          vy += __shfl_xor(vy, 32, 64);
          if (quad == 0) atomicAdd(&sY[Jb + ni * 16 + cl], vy);
        }
      }
    }
  }

  // T1 wave reduction (off-diagonal tiles count twice by symmetry)
  if (fmask != 0) {
    t1l *= offdiag ? 2.f : 1.f;
#pragma unroll
    for (int mm = 1; mm < 64; mm <<= 1) t1l += __shfl_xor(t1l, mm, 64);
    if (lane == 0 && t1l != 0.f) atomicAdd(T1, t1l);
  }

  // ---- fused final: per-WAVE completion counter; last wave computes HSIC.
  // All prior device-scope atomics are ordered before the release
  // fetch_add; the last wave's acquire makes them visible. g_done is a
  // __device__ global: unaffected by workspace poison, monotonic across
  // launches and rocprof replays (each launch adds exactly NBLK).
  int am_last = 0;
  if (lane == 0) {
    unsigned old = __hip_atomic_fetch_add(&g_done, 1u, __ATOMIC_ACQ_REL,
                                          __HIP_MEMORY_SCOPE_AGENT);
    am_last = ((old + 1u) % (unsigned)NBLK) == 0u;
  }
  am_last = __shfl(am_last, 0, 64);
  if (am_last) {
    float dp = 0.f, sa = 0.f, sb = 0.f;
    for (int i = lane; i < N; i += 64) {
      float a = __hip_atomic_load(&sX[i], __ATOMIC_RELAXED, __HIP_MEMORY_SCOPE_AGENT);
      float bv = __hip_atomic_load(&sY[i], __ATOMIC_RELAXED, __HIP_MEMORY_SCOPE_AGENT);
      dp += a * bv; sa += a; sb += bv;
    }
#pragma unroll
    for (int mm = 1; mm < 64; mm <<= 1) {
      dp += __shfl_xor(dp, mm, 64);
      sa += __shfl_xor(sa, mm, 64);
      sb += __shfl_xor(sb, mm, 64);
    }
    if (lane == 0) {
      const float t1 = __hip_atomic_load(T1, __ATOMIC_RELAXED, __HIP_MEMORY_SCOPE_AGENT);
      const float n = (float)N;
      const float total = t1 - (2.f / n) * dp + (sa * sb) / (n * n);
      out[0] = total / ((n - 1.f) * (n - 1.f));
    }
  }
}

}  // namespace

extern "C" void kernel_launch(void* const* d_in, const int* in_sizes, int n_in,
                              void* d_out, int out_size, void* d_ws, size_t ws_size,
                              hipStream_t stream) {
  const float* X = (const float*)d_in[0];
  const float* Y = (const float*)d_in[1];
  char* ws = (char*)d_ws;
  if (ws_size < WS_NEED) return;

  unsigned char* Xf8 = (unsigned char*)(ws + OFF_XB);
  unsigned char* Yf8 = (unsigned char*)(ws + OFF_YB);
  float* sqX = (float*)(ws + OFF_SQX);
  float* sqY = (float*)(ws + OFF_SQY);
  float* sX  = (float*)(ws + OFF_SX);
  float* sY  = (float*)(ws + OFF_SY);
  float* T1  = (float*)(ws + OFF_T1);
  float* out = (float*)d_out;

  prep_kernel<<<dim3(N / 4, 2), 256, 0, stream>>>(X, Y, Xf8, Yf8, sqX, sqY, sX, sY, T1);
  hsic_main<<<NGRID, 256, 0, stream>>>(Xf8, Yf8, sqX, sqY, sX, sY, T1, out);
}